// Round 3
// baseline (44.804 us; speedup 1.0000x reference)
//
#include <hip/hip_runtime.h>

// KroneckerLoss: per-row reductions over 4 fp32 [8192,1024] arrays + scalar MSE.
// a = sum(obs1_row); c = dot(obs2_row, [1,-1,...]); h1 = sum(hyp1_row); h2 = sum(hyp2_row)
// s1 = a*h1*c, s2 = a*h2*c; t1 = (label==1 ? 1 : -1), t2 = -t1
// out = sum_rows 0.5*((s1-t1)^2 + (s2-t2)^2)
//
// R3: full TLP (2048 blocks -> 32 waves/CU) AND full MLP (all 16 float4
// loads issued into an explicit register window before any consumption).
// R2 showed VGPR=36 => only ~4 loads in flight; this forces ~16.

constexpr int kB = 8192;
constexpr int kD = 1024;
constexpr int kWavesPerBlock = 4;            // 256 threads/block
constexpr int kChunks = (kD / 4) / 64;       // 4 float4 per lane per array

__global__ __launch_bounds__(256) void kron_loss_kernel(
    const float* __restrict__ obs1, const float* __restrict__ obs2,
    const float* __restrict__ hyp1, const float* __restrict__ hyp2,
    const int* __restrict__ labels, float* __restrict__ out)
{
    const int wave = threadIdx.x >> 6;
    const int lane = threadIdx.x & 63;
    const int row  = blockIdx.x * kWavesPerBlock + wave;   // grid sized exactly
    const size_t base = (size_t)row * kD;

    const float4* o1 = reinterpret_cast<const float4*>(obs1 + base);
    const float4* o2 = reinterpret_cast<const float4*>(obs2 + base);
    const float4* h1 = reinterpret_cast<const float4*>(hyp1 + base);
    const float4* h2 = reinterpret_cast<const float4*>(hyp2 + base);

    // ---- issue ALL 16 loads before any use: 16 x 1KB/wave in flight ----
    float4 v[4 * kChunks];
    #pragma unroll
    for (int k = 0; k < kChunks; ++k) v[k]              = o1[lane + 64 * k];
    #pragma unroll
    for (int k = 0; k < kChunks; ++k) v[kChunks + k]    = o2[lane + 64 * k];
    #pragma unroll
    for (int k = 0; k < kChunks; ++k) v[2*kChunks + k]  = h1[lane + 64 * k];
    #pragma unroll
    for (int k = 0; k < kChunks; ++k) v[3*kChunks + k]  = h2[lane + 64 * k];

    // ---- consume ----
    float a = 0.f, c = 0.f, b1 = 0.f, b2 = 0.f;
    #pragma unroll
    for (int k = 0; k < kChunks; ++k) {
        const float4 p = v[k];
        const float4 q = v[kChunks + k];
        const float4 r = v[2*kChunks + k];
        const float4 s = v[3*kChunks + k];
        a  += (p.x + p.y) + (p.z + p.w);
        c  += (q.x - q.y) + (q.z - q.w);   // alternating +/- by parity of flat idx
        b1 += (r.x + r.y) + (r.z + r.w);
        b2 += (s.x + s.y) + (s.z + s.w);
    }

    // 64-lane butterfly reduction; 4 independent chains give ILP.
    #pragma unroll
    for (int off = 32; off > 0; off >>= 1) {
        a  += __shfl_down(a,  off);
        c  += __shfl_down(c,  off);
        b1 += __shfl_down(b1, off);
        b2 += __shfl_down(b2, off);
    }

    __shared__ float partial[kWavesPerBlock];
    if (lane == 0) {
        const float t1 = (labels[row] == 1) ? 1.f : -1.f;  // t2 = -t1
        const float ac = a * c;
        const float s1 = ac * b1;
        const float s2 = ac * b2;
        const float d1 = s1 - t1;
        const float d2 = s2 + t1;
        partial[wave] = 0.5f * (d1 * d1 + d2 * d2);
    }
    __syncthreads();
    if (threadIdx.x == 0) {
        const float sum = (partial[0] + partial[1]) + (partial[2] + partial[3]);
        atomicAdd(out, sum);   // 2048 total, spread across block completions
    }
}

extern "C" void kernel_launch(void* const* d_in, const int* in_sizes, int n_in,
                              void* d_out, int out_size, void* d_ws, size_t ws_size,
                              hipStream_t stream) {
    const float* obs1   = (const float*)d_in[0];
    const float* obs2   = (const float*)d_in[1];
    const float* hyp1   = (const float*)d_in[2];
    const float* hyp2   = (const float*)d_in[3];
    const int*   labels = (const int*)d_in[4];
    float* out = (float*)d_out;

    // d_out is poisoned once and never re-poisoned between replays ->
    // zero it every call (graph-capture-safe async memset).
    hipMemsetAsync(out, 0, sizeof(float), stream);

    const int grid = kB / kWavesPerBlock;   // 2048 blocks x 256 threads
    kron_loss_kernel<<<grid, 256, 0, stream>>>(obs1, obs2, hyp1, hyp2, labels, out);
}

// Round 4
// 29.930 us; speedup vs baseline: 1.4970x; 1.4970x over previous
//
#include <hip/hip_runtime.h>

// KroneckerLoss: per-row reductions over 4 fp32 [8192,1024] arrays + scalar MSE.
// a = sum(obs1_row); c = dot(obs2_row, [1,-1,...]); h1 = sum(hyp1_row); h2 = sum(hyp2_row)
// s1 = a*h1*c, s2 = a*h2*c; t1 = (label==1 ? 1 : -1), t2 = -t1
// out = sum_rows 0.5*((s1-t1)^2 + (s2-t2)^2)
//
// R4: main kernel = R2's structure exactly (4 rows/wave, 512 blocks, 37us).
// Epilogue changed: per-block partial -> d_ws[blockIdx], then a 1-wave
// second kernel reduces 512 partials -> d_out. Eliminates all same-address
// atomics (R1/R3 vs R2 delta suggests the atomic tail costs ~8-15us).

constexpr int kB = 8192;
constexpr int kD = 1024;
constexpr int kWavesPerBlock = 4;        // 256 threads/block
constexpr int kRowsPerWave = 4;
constexpr int kRowsPerBlock = kWavesPerBlock * kRowsPerWave;  // 16
constexpr int kGrid = kB / kRowsPerBlock;                     // 512 blocks
constexpr int kChunksPerLane = (kD / 4) / 64;  // 4 float4 loads per lane per array per row

__global__ __launch_bounds__(256) void kron_loss_kernel(
    const float* __restrict__ obs1, const float* __restrict__ obs2,
    const float* __restrict__ hyp1, const float* __restrict__ hyp2,
    const int* __restrict__ labels, float* __restrict__ partials)
{
    const int wave = threadIdx.x >> 6;
    const int lane = threadIdx.x & 63;
    const int row0 = (blockIdx.x * kWavesPerBlock + wave) * kRowsPerWave;

    float a[kRowsPerWave], c[kRowsPerWave], b1[kRowsPerWave], b2[kRowsPerWave];

    #pragma unroll
    for (int r = 0; r < kRowsPerWave; ++r) {
        const size_t base = (size_t)(row0 + r) * kD;
        const float4* o1 = reinterpret_cast<const float4*>(obs1 + base);
        const float4* o2 = reinterpret_cast<const float4*>(obs2 + base);
        const float4* h1 = reinterpret_cast<const float4*>(hyp1 + base);
        const float4* h2 = reinterpret_cast<const float4*>(hyp2 + base);
        float ar = 0.f, cr = 0.f, b1r = 0.f, b2r = 0.f;
        #pragma unroll
        for (int k = 0; k < kChunksPerLane; ++k) {
            const int idx = lane + 64 * k;   // coalesced: 64 lanes x 16B = 1KB/instr
            float4 v1 = o1[idx];
            float4 v2 = o2[idx];
            float4 w1 = h1[idx];
            float4 w2 = h2[idx];
            ar  += (v1.x + v1.y) + (v1.z + v1.w);
            cr  += (v2.x - v2.y) + (v2.z - v2.w);  // alternating +/- by parity of flat idx
            b1r += (w1.x + w1.y) + (w1.z + w1.w);
            b2r += (w2.x + w2.y) + (w2.z + w2.w);
        }
        a[r] = ar; c[r] = cr; b1[r] = b1r; b2[r] = b2r;
    }

    // Batched 64-lane butterfly: 6 stages x 16 independent values.
    #pragma unroll
    for (int off = 32; off > 0; off >>= 1) {
        #pragma unroll
        for (int r = 0; r < kRowsPerWave; ++r) {
            a[r]  += __shfl_down(a[r],  off);
            c[r]  += __shfl_down(c[r],  off);
            b1[r] += __shfl_down(b1[r], off);
            b2[r] += __shfl_down(b2[r], off);
        }
    }

    __shared__ float partial[kWavesPerBlock];
    if (lane == 0) {
        float loss = 0.f;
        #pragma unroll
        for (int r = 0; r < kRowsPerWave; ++r) {
            const float t1 = (labels[row0 + r] == 1) ? 1.f : -1.f;  // t2 = -t1
            const float ac = a[r] * c[r];
            const float s1 = ac * b1[r];
            const float s2 = ac * b2[r];
            const float d1 = s1 - t1;
            const float d2 = s2 + t1;
            loss += 0.5f * (d1 * d1 + d2 * d2);
        }
        partial[wave] = loss;
    }
    __syncthreads();
    if (threadIdx.x == 0) {
        partials[blockIdx.x] = (partial[0] + partial[1]) + (partial[2] + partial[3]);
    }
}

// Reduce kGrid (=512) partials -> out[0]. One wave.
__global__ __launch_bounds__(64) void kron_loss_finish(
    const float* __restrict__ partials, float* __restrict__ out)
{
    const int lane = threadIdx.x;  // 0..63
    const float4* p4 = reinterpret_cast<const float4*>(partials);
    // 512 floats = 128 float4; 64 lanes x 2 float4
    float4 u = p4[lane];
    float4 v = p4[lane + 64];
    float s = ((u.x + u.y) + (u.z + u.w)) + ((v.x + v.y) + (v.z + v.w));
    #pragma unroll
    for (int off = 32; off > 0; off >>= 1) s += __shfl_down(s, off);
    if (lane == 0) out[0] = s;
}

extern "C" void kernel_launch(void* const* d_in, const int* in_sizes, int n_in,
                              void* d_out, int out_size, void* d_ws, size_t ws_size,
                              hipStream_t stream) {
    const float* obs1   = (const float*)d_in[0];
    const float* obs2   = (const float*)d_in[1];
    const float* hyp1   = (const float*)d_in[2];
    const float* hyp2   = (const float*)d_in[3];
    const int*   labels = (const int*)d_in[4];
    float* out      = (float*)d_out;
    float* partials = (float*)d_ws;   // 512 floats, fully overwritten every call

    kron_loss_kernel<<<kGrid, 256, 0, stream>>>(obs1, obs2, hyp1, hyp2, labels, partials);
    kron_loss_finish<<<1, 64, 0, stream>>>(partials, out);
}

// Round 5
// 26.346 us; speedup vs baseline: 1.7006x; 1.1360x over previous
//
#include <hip/hip_runtime.h>

// KroneckerLoss: per-row reductions over 4 fp32 [8192,1024] arrays + scalar MSE.
// a = sum(obs1_row); c = dot(obs2_row, [1,-1,...]); h1 = sum(hyp1_row); h2 = sum(hyp2_row)
// s1 = a*h1*c, s2 = a*h2*c; t1 = (label==1 ? 1 : -1), t2 = -t1
// out = sum_rows 0.5*((s1-t1)^2 + (s2-t2)^2)
//
// R5: occupancy test. R4 (8 waves/CU, no atomics) = 29.9us @ ~5.2 TB/s eff.
// Same body, but 2048 blocks x 4 waves x 1 row/wave = 32 waves/CU (max TLP).
// No same-address atomics anywhere (R4's win): per-block partial -> d_ws,
// 256-thread finish kernel reduces 2048 partials.

constexpr int kB = 8192;
constexpr int kD = 1024;
constexpr int kWavesPerBlock = 4;            // 256 threads/block
constexpr int kGrid = kB / kWavesPerBlock;   // 2048 blocks, 1 row/wave
constexpr int kChunks = (kD / 4) / 64;       // 4 float4 loads per lane per array

__global__ __launch_bounds__(256) void kron_loss_kernel(
    const float* __restrict__ obs1, const float* __restrict__ obs2,
    const float* __restrict__ hyp1, const float* __restrict__ hyp2,
    const int* __restrict__ labels, float* __restrict__ partials)
{
    const int wave = threadIdx.x >> 6;
    const int lane = threadIdx.x & 63;
    const int row  = blockIdx.x * kWavesPerBlock + wave;
    const size_t base = (size_t)row * kD;

    const float4* o1 = reinterpret_cast<const float4*>(obs1 + base);
    const float4* o2 = reinterpret_cast<const float4*>(obs2 + base);
    const float4* h1 = reinterpret_cast<const float4*>(hyp1 + base);
    const float4* h2 = reinterpret_cast<const float4*>(hyp2 + base);

    float a = 0.f, c = 0.f, b1 = 0.f, b2 = 0.f;
    #pragma unroll
    for (int k = 0; k < kChunks; ++k) {
        const int idx = lane + 64 * k;   // coalesced: 64 lanes x 16B = 1KB/instr
        float4 v1 = o1[idx];
        float4 v2 = o2[idx];
        float4 w1 = h1[idx];
        float4 w2 = h2[idx];
        a  += (v1.x + v1.y) + (v1.z + v1.w);
        c  += (v2.x - v2.y) + (v2.z - v2.w);  // alternating +/- by parity of flat idx
        b1 += (w1.x + w1.y) + (w1.z + w1.w);
        b2 += (w2.x + w2.y) + (w2.z + w2.w);
    }

    // 64-lane butterfly; 4 independent chains give ILP.
    #pragma unroll
    for (int off = 32; off > 0; off >>= 1) {
        a  += __shfl_down(a,  off);
        c  += __shfl_down(c,  off);
        b1 += __shfl_down(b1, off);
        b2 += __shfl_down(b2, off);
    }

    __shared__ float partial[kWavesPerBlock];
    if (lane == 0) {
        const float t1 = (labels[row] == 1) ? 1.f : -1.f;  // t2 = -t1
        const float ac = a * c;
        const float s1 = ac * b1;
        const float s2 = ac * b2;
        const float d1 = s1 - t1;
        const float d2 = s2 + t1;
        partial[wave] = 0.5f * (d1 * d1 + d2 * d2);
    }
    __syncthreads();
    if (threadIdx.x == 0) {
        partials[blockIdx.x] = (partial[0] + partial[1]) + (partial[2] + partial[3]);
    }
}

// Reduce kGrid (=2048) partials -> out[0]. One 256-thread block.
__global__ __launch_bounds__(256) void kron_loss_finish(
    const float* __restrict__ partials, float* __restrict__ out)
{
    const int tid  = threadIdx.x;
    const int wave = tid >> 6;
    const int lane = tid & 63;
    const float4* p4 = reinterpret_cast<const float4*>(partials);
    // 2048 floats = 512 float4; 256 threads x 2 float4
    float4 u = p4[tid];
    float4 v = p4[tid + 256];
    float s = ((u.x + u.y) + (u.z + u.w)) + ((v.x + v.y) + (v.z + v.w));
    #pragma unroll
    for (int off = 32; off > 0; off >>= 1) s += __shfl_down(s, off);
    __shared__ float ps[4];
    if (lane == 0) ps[wave] = s;
    __syncthreads();
    if (tid == 0) out[0] = (ps[0] + ps[1]) + (ps[2] + ps[3]);
}

extern "C" void kernel_launch(void* const* d_in, const int* in_sizes, int n_in,
                              void* d_out, int out_size, void* d_ws, size_t ws_size,
                              hipStream_t stream) {
    const float* obs1   = (const float*)d_in[0];
    const float* obs2   = (const float*)d_in[1];
    const float* hyp1   = (const float*)d_in[2];
    const float* hyp2   = (const float*)d_in[3];
    const int*   labels = (const int*)d_in[4];
    float* out      = (float*)d_out;
    float* partials = (float*)d_ws;   // 2048 floats, fully overwritten every call

    kron_loss_kernel<<<kGrid, 256, 0, stream>>>(obs1, obs2, hyp1, hyp2, labels, partials);
    kron_loss_finish<<<1, 256, 0, stream>>>(partials, out);
}

// Round 7
// 25.634 us; speedup vs baseline: 1.7478x; 1.0278x over previous
//
#include <hip/hip_runtime.h>

// KroneckerLoss: per-row reductions over 4 fp32 [8192,1024] arrays + scalar MSE.
// a = sum(obs1_row); c = dot(obs2_row, [1,-1,...]); h1 = sum(hyp1_row); h2 = sum(hyp2_row)
// s1 = a*h1*c, s2 = a*h2*c; t1 = (label==1 ? 1 : -1), t2 = -t1
// out = sum_rows 0.5*((s1-t1)^2 + (s2-t2)^2)
//
// R7 == R6 design, compile-fixed: __builtin_nontemporal_load needs a native
// vector type, not HIP_vector_type -> use ext_vector_type(4) float.
//  - 1 wave per block (8192 x 64thr): no LDS/__syncthreads epilogue,
//    blocks retire independently (same 32 waves/CU TLP as R5).
//  - nontemporal loads: streaming data, zero reuse.
//  - NO same-address atomics (R1 vs R5: 2048 of them cost ~19us).

typedef float vf4 __attribute__((ext_vector_type(4)));

constexpr int kB = 8192;
constexpr int kD = 1024;
constexpr int kChunks = (kD / 4) / 64;       // 4 float4 loads per lane per array

__global__ __launch_bounds__(64) void kron_loss_kernel(
    const float* __restrict__ obs1, const float* __restrict__ obs2,
    const float* __restrict__ hyp1, const float* __restrict__ hyp2,
    const int* __restrict__ labels, float* __restrict__ partials)
{
    const int lane = threadIdx.x;            // 64-thread block = 1 wave
    const int row  = blockIdx.x;
    const size_t base = (size_t)row * kD;

    const vf4* o1 = reinterpret_cast<const vf4*>(obs1 + base);
    const vf4* o2 = reinterpret_cast<const vf4*>(obs2 + base);
    const vf4* h1 = reinterpret_cast<const vf4*>(hyp1 + base);
    const vf4* h2 = reinterpret_cast<const vf4*>(hyp2 + base);

    float a = 0.f, c = 0.f, b1 = 0.f, b2 = 0.f;
    #pragma unroll
    for (int k = 0; k < kChunks; ++k) {
        const int idx = lane + 64 * k;       // coalesced: 64 lanes x 16B = 1KB/instr
        vf4 v1 = __builtin_nontemporal_load(&o1[idx]);
        vf4 v2 = __builtin_nontemporal_load(&o2[idx]);
        vf4 w1 = __builtin_nontemporal_load(&h1[idx]);
        vf4 w2 = __builtin_nontemporal_load(&h2[idx]);
        a  += (v1.x + v1.y) + (v1.z + v1.w);
        c  += (v2.x - v2.y) + (v2.z - v2.w);  // alternating +/- by parity of flat idx
        b1 += (w1.x + w1.y) + (w1.z + w1.w);
        b2 += (w2.x + w2.y) + (w2.z + w2.w);
    }

    // 64-lane butterfly; 4 independent chains give ILP.
    #pragma unroll
    for (int off = 32; off > 0; off >>= 1) {
        a  += __shfl_down(a,  off);
        c  += __shfl_down(c,  off);
        b1 += __shfl_down(b1, off);
        b2 += __shfl_down(b2, off);
    }

    if (lane == 0) {
        const float t1 = (labels[row] == 1) ? 1.f : -1.f;  // t2 = -t1
        const float ac = a * c;
        const float s1 = ac * b1;
        const float s2 = ac * b2;
        const float d1 = s1 - t1;
        const float d2 = s2 + t1;
        partials[row] = 0.5f * (d1 * d1 + d2 * d2);
    }
}

// Reduce kB (=8192) partials -> out[0]. One 256-thread block.
__global__ __launch_bounds__(256) void kron_loss_finish(
    const float* __restrict__ partials, float* __restrict__ out)
{
    const int tid  = threadIdx.x;
    const int wave = tid >> 6;
    const int lane = tid & 63;
    const vf4* p4 = reinterpret_cast<const vf4*>(partials);
    // 8192 floats = 2048 float4; 256 threads x 8 float4
    float s = 0.f;
    #pragma unroll
    for (int k = 0; k < 8; ++k) {
        vf4 u = p4[tid + 256 * k];
        s += (u.x + u.y) + (u.z + u.w);
    }
    #pragma unroll
    for (int off = 32; off > 0; off >>= 1) s += __shfl_down(s, off);
    __shared__ float ps[4];
    if (lane == 0) ps[wave] = s;
    __syncthreads();
    if (tid == 0) out[0] = (ps[0] + ps[1]) + (ps[2] + ps[3]);
}

extern "C" void kernel_launch(void* const* d_in, const int* in_sizes, int n_in,
                              void* d_out, int out_size, void* d_ws, size_t ws_size,
                              hipStream_t stream) {
    const float* obs1   = (const float*)d_in[0];
    const float* obs2   = (const float*)d_in[1];
    const float* hyp1   = (const float*)d_in[2];
    const float* hyp2   = (const float*)d_in[3];
    const int*   labels = (const int*)d_in[4];
    float* out      = (float*)d_out;
    float* partials = (float*)d_ws;   // 8192 floats, fully overwritten every call

    kron_loss_kernel<<<kB, 64, 0, stream>>>(obs1, obs2, hyp1, hyp2, labels, partials);
    kron_loss_finish<<<1, 256, 0, stream>>>(partials, out);
}